// Round 17
// baseline (404.772 us; speedup 1.0000x reference)
//
#include <hip/hip_runtime.h>

typedef unsigned short u16;
typedef unsigned char u8;
typedef unsigned int u32;

using bfrag  = __attribute__((ext_vector_type(8))) short;   // 8 bf16 (4 VGPRs)
using f32x2  = __attribute__((ext_vector_type(2))) float;
using f32x4  = __attribute__((ext_vector_type(4))) float;   // 4 fp32 acc
using f32x16 = __attribute__((ext_vector_type(16))) float;  // 16 fp32 acc (32x32 MFMA)

// ---------- bf16 / f16 / fp8 helpers ----------
__device__ __forceinline__ float b2f(u16 u) {
  union { u32 i; float f; } c; c.i = ((u32)u) << 16; return c.f;
}
__device__ __forceinline__ float bflo(u32 u) { union { u32 i; float f; } c; c.i = u << 16; return c.f; }
__device__ __forceinline__ float bfhi(u32 u) { union { u32 i; float f; } c; c.i = u & 0xffff0000u; return c.f; }
__device__ __forceinline__ u16 f2b(float f) {  // round-to-nearest-even
  union { float f; u32 i; } c; c.f = f;
  u32 x = c.i;
  u32 r = x + 0x7fffu + ((x >> 16) & 1u);
  return (u16)(r >> 16);
}
__device__ __forceinline__ u32 packb2(float x, float y) {
  return ((u32)f2b(x)) | (((u32)f2b(y)) << 16);
}
__device__ __forceinline__ int rfl(int v) { return __builtin_amdgcn_readfirstlane(v); }

// ---------- count_deg: own kernel so scan starts immediately after ----------
__global__ __launch_bounds__(256) void count_deg(const int* __restrict__ eidx,
                                                 int* __restrict__ degi, int E) {
  int e = blockIdx.x * 256 + threadIdx.x;
  if (e >= E) return;
  atomicAdd(&degi[eidx[E + e]], 1);
  atomicAdd(&degi[eidx[e]], 1);
}

// ---------- parallel scan ----------
__global__ __launch_bounds__(256) void scan1(const int* __restrict__ degi,
                                             int* __restrict__ bsum, int N) {
  __shared__ int sh[256];
  int t = threadIdx.x;
  int gid = blockIdx.x * 256 + t;
  sh[t] = (gid < N) ? degi[gid] : 0;
  __syncthreads();
  for (int off = 128; off > 0; off >>= 1) {
    if (t < off) sh[t] += sh[t + off];
    __syncthreads();
  }
  if (t == 0) bsum[blockIdx.x] = sh[0];
}

__global__ __launch_bounds__(256) void scan23(const int* __restrict__ degi,
                                              const int* __restrict__ bsum,
                                              int* __restrict__ rowptr,
                                              int* __restrict__ cursor,
                                              float* __restrict__ dis, int nb, int N) {
  __shared__ int sh[256];
  int t = threadIdx.x;
  int v = (t < nb) ? bsum[t] : 0;
  sh[t] = v;
  __syncthreads();
  for (int off = 1; off < 256; off <<= 1) {
    int x = sh[t];
    int add = (t >= off) ? sh[t - off] : 0;
    __syncthreads();
    sh[t] = x + add;
    __syncthreads();
  }
  int blockoff = (blockIdx.x == 0) ? 0 : sh[blockIdx.x - 1];
  int total = sh[nb - 1];
  __syncthreads();
  int gid = blockIdx.x * 256 + t;
  int d = (gid < N) ? degi[gid] : 0;
  sh[t] = d;
  __syncthreads();
  for (int off = 1; off < 256; off <<= 1) {
    int x = sh[t];
    int add = (t >= off) ? sh[t - off] : 0;
    __syncthreads();
    sh[t] = x + add;
    __syncthreads();
  }
  if (gid < N) {
    int run = blockoff + sh[t] - d;
    rowptr[gid] = run;
    cursor[gid] = run;
    dis[gid] = d > 0 ? rsqrtf((float)d) : 0.0f;
  }
  if (blockIdx.x == 0 && t == 0) rowptr[N] = total;
}

// ---------- mega: [0,PB) proj; [PB,PB+112) prep_wt; [.,+FB) fill_csr; rest head MLP ----------
__global__ __launch_bounds__(256) void mega(
    const float* __restrict__ ea, const int* __restrict__ eidx,
    const float* __restrict__ ea0_w1, const float* __restrict__ ea0_b1,
    const float* __restrict__ ea0_w2,
    const float* __restrict__ tag0_w, const float* __restrict__ ea1_w1,
    const float* __restrict__ ea1_w2, const float* __restrict__ tag1_w,
    const float* __restrict__ ea2_w1,
    const float* __restrict__ mask, const float* __restrict__ x,
    const float* __restrict__ m_w1, const float* __restrict__ m_b1,
    const float* __restrict__ m_w2, const float* __restrict__ m_b2,
    u8* __restrict__ P0, u8* __restrict__ P1, u8* __restrict__ P2,
    u16* __restrict__ Wt, int* __restrict__ cursor,
    const float* __restrict__ dis, int4* __restrict__ cr,
    u16* __restrict__ pb, u16* __restrict__ q,
    int E, int N, int PB, int FB, int EB) {
  int t = threadIdx.x;
  if (blockIdx.x < (unsigned)PB) {
    // ---- edge projection via MFMA 32x32x16: P[e,:] = ea[e,:16] @ W_tab (fp8 e4m3) ----
    __shared__ u16 Alds[256 * 16];
    __shared__ u16 Wlds[2048];
    int tab = blockIdx.x / EB;
    int chunk = blockIdx.x - tab * EB;
    int base = chunk * 256;
    int rows = E - base; if (rows > 256) rows = 256;
    const float* wsrc = (tab == 0) ? (ea0_w1 + 32 * 128)
                      : (tab == 1) ? (ea1_w1 + 256 * 128)
                                   : (ea2_w1 + 256 * 128);
    u8* P = (tab == 0) ? P0 : (tab == 1) ? P1 : P2;
#pragma unroll
    for (int i = 0; i < 8; ++i) {
      int idx = i * 256 + t;
      int n = idx >> 4, k = idx & 15;
      Wlds[idx] = f2b(wsrc[k * 128 + n]);
    }
#pragma unroll
    for (int i = 0; i < 4; ++i) {
      int idx = (i * 256 + t) * 4;
      float4 v = make_float4(0.f, 0.f, 0.f, 0.f);
      if ((idx >> 4) < rows) v = *(const float4*)(ea + (size_t)base * 16 + idx);
      ushort4 h;
      h.x = f2b(v.x); h.y = f2b(v.y); h.z = f2b(v.z); h.w = f2b(v.w);
      *(ushort4*)(Alds + idx) = h;
    }
    __syncthreads();
    int wave = t >> 6, lane = t & 63;
    int mm = lane & 31, kh = lane >> 5;
    bfrag b00 = *(const bfrag*)(Wlds + (2 * mm) * 16 + kh * 8);
    bfrag b01 = *(const bfrag*)(Wlds + (2 * mm + 1) * 16 + kh * 8);
    bfrag b10 = *(const bfrag*)(Wlds + (64 + 2 * mm) * 16 + kh * 8);
    bfrag b11 = *(const bfrag*)(Wlds + (64 + 2 * mm + 1) * 16 + kh * 8);
#pragma unroll
    for (int it = 0; it < 4; ++it) {
      int task = wave + it * 4;
      int rowt = (task >> 1) * 32;
      int ch = task & 1;
      int colt = ch * 64;
      bfrag a = *(const bfrag*)(Alds + (rowt + mm) * 16 + kh * 8);
      f32x16 acc0, acc1;
#pragma unroll
      for (int z = 0; z < 16; ++z) { acc0[z] = 0.f; acc1[z] = 0.f; }
      acc0 = __builtin_amdgcn_mfma_f32_32x32x16_bf16(a, ch ? b10 : b00, acc0, 0, 0, 0);
      acc1 = __builtin_amdgcn_mfma_f32_32x32x16_bf16(a, ch ? b11 : b01, acc1, 0, 0, 0);
#pragma unroll
      for (int reg = 0; reg < 16; ++reg) {
        int row = rowt + (reg & 3) + 8 * (reg >> 2) + 4 * kh;
        if (row < rows) {
          u32 pk = (u32)__builtin_amdgcn_cvt_pk_fp8_f32(acc0[reg], acc1[reg], 0, false);
          *(u16*)(P + (size_t)(base + row) * 128 + colt + 2 * mm) = (u16)pk;
        }
      }
    }
    return;
  }
  if (blockIdx.x < (unsigned)(PB + 112)) {
    // ---- prep_wt: 14x fp32 [128][128] -> bf16 [n][k] ----
    int wb = blockIdx.x - PB;
    int mat = wb >> 3, chunk = wb & 7;
    const float* src;
    if      (mat == 0)  src = ea0_w2;
    else if (mat <= 4)  src = tag0_w + (mat - 1) * 16384;
    else if (mat == 5)  src = ea1_w1;
    else if (mat == 6)  src = ea1_w1 + 16384;
    else if (mat == 7)  src = ea1_w2;
    else if (mat <= 11) src = tag1_w + (mat - 8) * 16384;
    else if (mat == 12) src = ea2_w1;
    else                src = ea2_w1 + 16384;
    u16* dst = Wt + mat * 16384;
    for (int i = 0; i < 8; ++i) {
      int idx = chunk * 2048 + i * 256 + t;
      int k = idx >> 7, n = idx & 127;
      dst[n * 128 + k] = f2b(src[idx]);
    }
    return;
  }
  if (blockIdx.x < (unsigned)(PB + 112 + FB)) {
    // ---- fill_csr: unified 16B records (cursor pre-seeded by scan23) ----
    int i = (blockIdx.x - PB - 112) * 256 + t;
    int E2 = 2 * E;
    if (i >= E2) return;
    int e = (i < E) ? i : i - E;
    int s, d;
    if (i < E) { s = eidx[e]; d = eidx[E + e]; }
    else       { s = eidx[E + e]; d = eidx[e]; }
    int pos = atomicAdd(&cursor[d], 1);
    cr[pos] = make_int4(s, e, __float_as_int(dis[s]), 0);
    return;
  }
  // ---- head: h16 = relu(mask@w1+b1)@w2 + b2 + x; pb = h16@Wd + b1', q = h16@Ws ----
  __shared__ float Ml[16 * 16];
  __shared__ float T1[16 * 128];
  __shared__ float H[16 * 16];
  int base = (blockIdx.x - PB - 112 - FB) * 16;
  {
    int r = t >> 4, k = t & 15;
    int row = base + r;
    Ml[t] = (row < N) ? mask[(size_t)row * 16 + k] : 0.f;
  }
  __syncthreads();
  {
    int col = t & 127, h2 = t >> 7;
    float acc[8];
    float b1v = m_b1[col];
#pragma unroll
    for (int r = 0; r < 8; ++r) acc[r] = b1v;
    for (int k = 0; k < 16; ++k) {
      float w = m_w1[k * 128 + col];
#pragma unroll
      for (int r = 0; r < 8; ++r) acc[r] += Ml[(h2 * 8 + r) * 16 + k] * w;
    }
#pragma unroll
    for (int r = 0; r < 8; ++r) T1[(h2 * 8 + r) * 128 + col] = fmaxf(acc[r], 0.f);
  }
  __syncthreads();
  {
    int r = t >> 4, u = t & 15;
    float acc = m_b2[u];
    for (int k = 0; k < 128; ++k) acc += T1[r * 128 + k] * m_w2[k * 16 + u];
    int row = base + r;
    float xv = (row < N) ? x[(size_t)row * 16 + u] : 0.f;
    H[t] = acc + xv;
  }
  __syncthreads();
  {
    int col = t & 127, h2 = t >> 7;
    float aP[8], aQ[8];
    float b1v = ea0_b1[col];
#pragma unroll
    for (int r = 0; r < 8; ++r) { aP[r] = b1v; aQ[r] = 0.f; }
    for (int k = 0; k < 16; ++k) {
      float wd = ea0_w1[k * 128 + col];
      float ws = ea0_w1[(16 + k) * 128 + col];
#pragma unroll
      for (int r = 0; r < 8; ++r) {
        float h = H[(h2 * 8 + r) * 16 + k];
        aP[r] += h * wd;
        aQ[r] += h * ws;
      }
    }
#pragma unroll
    for (int r = 0; r < 8; ++r) {
      int row = base + h2 * 8 + r;
      if (row < N) {
        pb[(size_t)row * 128 + col] = f2b(aP[r]);
        q[(size_t)row * 128 + col]  = f2b(aQ[r]);
      }
    }
  }
}

// ---------- dual MFMA GEMM: C0 = A@W0 (+bias0), C1 = A@W1 (both bf16) ----------
__global__ __launch_bounds__(256) void gemm_mfma_dual(
    const u16* __restrict__ A, const u16* __restrict__ W0t, const u16* __restrict__ W1t,
    u16* __restrict__ C0, u16* __restrict__ C1, const float* __restrict__ bias0, int M) {
  __shared__ u16 Alds[64 * 136];
  __shared__ u16 Wlds[128 * 136];
  int t = threadIdx.x;
  int base = blockIdx.x * 64;
#pragma unroll
  for (int i = 0; i < 8; ++i) {
    int idx = (i * 256 + t) * 8;
    int n = idx >> 7, k = idx & 127;
    uint4 v = *(const uint4*)(W0t + idx);
    *(uint4*)(Wlds + n * 136 + k) = v;
  }
#pragma unroll
  for (int i = 0; i < 4; ++i) {
    int idx = (i * 256 + t) * 8;
    int r = idx >> 7, k = idx & 127;
    int row = base + r;
    uint4 v = make_uint4(0, 0, 0, 0);
    if (row < M) v = *(const uint4*)(A + (size_t)row * 128 + k);
    *(uint4*)(Alds + r * 136 + k) = v;
  }
  __syncthreads();
  int wave = t >> 6, lane = t & 63;
  int m = lane & 15, quad = lane >> 4;
  int arow = wave * 16 + m;
  bfrag a[4];
#pragma unroll
  for (int ks = 0; ks < 4; ++ks)
    a[ks] = *(const bfrag*)(Alds + arow * 136 + ks * 32 + quad * 8);
  f32x4 acc0[8], acc1[8];
#pragma unroll
  for (int nt = 0; nt < 8; ++nt) { acc0[nt] = (f32x4){0,0,0,0}; acc1[nt] = (f32x4){0,0,0,0}; }
#pragma unroll
  for (int nt = 0; nt < 8; ++nt) {
    int n = nt * 16 + m;
#pragma unroll
    for (int ks = 0; ks < 4; ++ks) {
      bfrag b = *(const bfrag*)(Wlds + n * 136 + ks * 32 + quad * 8);
      acc0[nt] = __builtin_amdgcn_mfma_f32_16x16x32_bf16(a[ks], b, acc0[nt], 0, 0, 0);
    }
  }
  __syncthreads();
#pragma unroll
  for (int i = 0; i < 8; ++i) {
    int idx = (i * 256 + t) * 8;
    int n = idx >> 7, k = idx & 127;
    uint4 v = *(const uint4*)(W1t + idx);
    *(uint4*)(Wlds + n * 136 + k) = v;
  }
  __syncthreads();
#pragma unroll
  for (int nt = 0; nt < 8; ++nt) {
    int n = nt * 16 + m;
#pragma unroll
    for (int ks = 0; ks < 4; ++ks) {
      bfrag b = *(const bfrag*)(Wlds + n * 136 + ks * 32 + quad * 8);
      acc1[nt] = __builtin_amdgcn_mfma_f32_16x16x32_bf16(a[ks], b, acc1[nt], 0, 0, 0);
    }
  }
#pragma unroll
  for (int nt = 0; nt < 8; ++nt) {
    int col = nt * 16 + m;
#pragma unroll
    for (int r = 0; r < 4; ++r) {
      int row = base + wave * 16 + quad * 4 + r;
      if (row < M) {
        float v0 = acc0[nt][r];
        if (bias0) v0 += bias0[col];
        C0[(size_t)row * 128 + col] = f2b(v0);
        C1[(size_t)row * 128 + col] = f2b(acc1[nt][r]);
      }
    }
  }
}

// ---------- penta MFMA GEMM: h = relu(A@W2 + deg*bias); G_k = h @ W_k (k=0..3) ----------
__global__ __launch_bounds__(256) void gemm_mfma_penta(
    const u16* __restrict__ A, const u16* __restrict__ W2t, const u16* __restrict__ Wt4,
    const float* __restrict__ bias, const int* __restrict__ degi,
    u16* __restrict__ G0, u16* __restrict__ G1,
    u16* __restrict__ G2, u16* __restrict__ G3, int M) {
  __shared__ u16 Alds[64 * 136];
  __shared__ u16 Wlds[128 * 136];
  int t = threadIdx.x;
  int base = blockIdx.x * 64;
#pragma unroll
  for (int i = 0; i < 8; ++i) {
    int idx = (i * 256 + t) * 8;
    int n = idx >> 7, k = idx & 127;
    uint4 v = *(const uint4*)(W2t + idx);
    *(uint4*)(Wlds + n * 136 + k) = v;
  }
#pragma unroll
  for (int i = 0; i < 4; ++i) {
    int idx = (i * 256 + t) * 8;
    int r = idx >> 7, k = idx & 127;
    int row = base + r;
    uint4 v = make_uint4(0, 0, 0, 0);
    if (row < M) v = *(const uint4*)(A + (size_t)row * 128 + k);
    *(uint4*)(Alds + r * 136 + k) = v;
  }
  __syncthreads();
  int wave = t >> 6, lane = t & 63;
  int m = lane & 15, quad = lane >> 4;
  int arow = wave * 16 + m;
  bfrag a[4];
#pragma unroll
  for (int ks = 0; ks < 4; ++ks)
    a[ks] = *(const bfrag*)(Alds + arow * 136 + ks * 32 + quad * 8);
  {
    f32x4 acc[8];
#pragma unroll
    for (int nt = 0; nt < 8; ++nt) acc[nt] = (f32x4){0.f, 0.f, 0.f, 0.f};
#pragma unroll
    for (int nt = 0; nt < 8; ++nt) {
      int n = nt * 16 + m;
#pragma unroll
      for (int ks = 0; ks < 4; ++ks) {
        bfrag b = *(const bfrag*)(Wlds + n * 136 + ks * 32 + quad * 8);
        acc[nt] = __builtin_amdgcn_mfma_f32_16x16x32_bf16(a[ks], b, acc[nt], 0, 0, 0);
      }
    }
#pragma unroll
    for (int nt = 0; nt < 8; ++nt) {
      int col = nt * 16 + m;
#pragma unroll
      for (int r = 0; r < 4; ++r) {
        int lrow = wave * 16 + quad * 4 + r;
        int row = base + lrow;
        float v = 0.f;
        if (row < M) v = fmaxf(acc[nt][r] + bias[col] * (float)degi[row], 0.f);
        Alds[lrow * 136 + col] = f2b(v);   // own wave's slab; in-wave DS ordering
      }
    }
  }
#pragma unroll
  for (int ks = 0; ks < 4; ++ks)
    a[ks] = *(const bfrag*)(Alds + arow * 136 + ks * 32 + quad * 8);
#pragma unroll
  for (int mat = 0; mat < 4; ++mat) {
    __syncthreads();
#pragma unroll
    for (int i = 0; i < 8; ++i) {
      int idx = (i * 256 + t) * 8;
      int n = idx >> 7, k = idx & 127;
      uint4 v = *(const uint4*)(Wt4 + mat * 16384 + idx);
      *(uint4*)(Wlds + n * 136 + k) = v;
    }
    __syncthreads();
    f32x4 acc[8];
#pragma unroll
    for (int nt = 0; nt < 8; ++nt) acc[nt] = (f32x4){0.f, 0.f, 0.f, 0.f};
#pragma unroll
    for (int nt = 0; nt < 8; ++nt) {
      int n = nt * 16 + m;
#pragma unroll
      for (int ks = 0; ks < 4; ++ks) {
        bfrag b = *(const bfrag*)(Wlds + n * 136 + ks * 32 + quad * 8);
        acc[nt] = __builtin_amdgcn_mfma_f32_16x16x32_bf16(a[ks], b, acc[nt], 0, 0, 0);
      }
    }
    u16* G = (mat == 0) ? G0 : (mat == 1) ? G1 : (mat == 2) ? G2 : G3;
#pragma unroll
    for (int nt = 0; nt < 8; ++nt) {
      int col = nt * 16 + m;
#pragma unroll
      for (int r = 0; r < 4; ++r) {
        int row = base + wave * 16 + quad * 4 + r;
        if (row < M) G[(size_t)row * 128 + col] = f2b(acc[nt][r]);
      }
    }
  }
}

// ---------- VALU GEMM (final 128->16) ----------
__global__ __launch_bounds__(128) void gemm_tail(
    const u16* __restrict__ A, const float* __restrict__ W, float* __restrict__ Cout,
    const float* __restrict__ bias, const int* __restrict__ degi, int M) {
  const int ROWS = 8;
  int t = threadIdx.x;
  int base = blockIdx.x * ROWS;
  __shared__ float Al[ROWS * 128];
  for (int i = t; i < ROWS * 128; i += 128) {
    int r = i >> 7, k = i & 127;
    int row = base + r;
    Al[i] = (row < M) ? b2f(A[(size_t)row * 128 + k]) : 0.f;
  }
  __syncthreads();
  int r = t >> 4, u = t & 15;
  int row = base + r;
  float acc = 0.f;
  for (int k = 0; k < 128; ++k) acc += Al[r * 128 + k] * W[k * 16 + u];
  if (row < M) {
    Cout[(size_t)row * 16 + u] = acc + bias[u] * (float)degi[row];
  }
}

// ---------- per-edge bodies (unified int4 records in LDS) ----------
__device__ __forceinline__ void tag_edge(const int4* __restrict__ rr, int j,
    const u16* __restrict__ g, int lane, float& x0, float& x1) {
  int4 r = rr[j];
  int s = rfl(r.x); float w = __uint_as_float(rfl(r.z));
  u32 h = *((const u32*)(g + (size_t)s * 128) + lane);
  x0 += w * bflo(h); x1 += w * bfhi(h);
}
__device__ __forceinline__ void ea_edge(const int4* __restrict__ rr, int j,
    const u16* __restrict__ q, const u8* __restrict__ P8, int lane,
    float pb0, float pb1, float& x0, float& x1) {
  int4 r = rr[j];
  int s = rfl(r.x), i = rfl(r.y);
  u32 qv = *((const u32*)(q + (size_t)s * 128) + lane);
  u16 pv = *((const u16*)(P8 + (size_t)i * 128) + lane);
  f32x2 pf = __builtin_amdgcn_cvt_pk_f32_fp8((int)pv, false);
  x0 += fmaxf(pb0 + bflo(qv) + pf.x, 0.f);
  x1 += fmaxf(pb1 + bfhi(qv) + pf.y, 0.f);
}

// ---------- TAG gather v9: 1 node/wave, LDS-staged 64-record batches, 8-edge unroll ----------
template<bool FINAL>
__global__ __launch_bounds__(256) void tag_gather9(
    const u16* __restrict__ g, const u16* __restrict__ Cin,
    const float* __restrict__ bias, const float* __restrict__ dis,
    const int* __restrict__ rowptr, const int4* __restrict__ cr,
    u16* __restrict__ out, int N) {
  __shared__ int4 recs[4][64];
  int wave = threadIdx.x >> 6, lane = threadIdx.x & 63;
  int node = blockIdx.x * 4 + wave;
  if (node >= N) return;
  int e0 = rfl(rowptr[node]);
  int e1 = rfl(rowptr[node + 1]);
  int4* rr = recs[wave];
  float a0 = 0, a1 = 0, b0 = 0, b1 = 0;
  for (int base = e0; base < e1; base += 64) {
    if (base + lane < e1) rr[lane] = cr[base + lane];
    int cnt = min(64, e1 - base);
    int j = 0;
    for (; j + 8 <= cnt; j += 8) {
      tag_edge(rr, j + 0, g, lane, a0, a1);
      tag_edge(rr, j + 1, g, lane, b0, b1);
      tag_edge(rr, j + 2, g, lane, a0, a1);
      tag_edge(rr, j + 3, g, lane, b0, b1);
      tag_edge(rr, j + 4, g, lane, a0, a1);
      tag_edge(rr, j + 5, g, lane, b0, b1);
      tag_edge(rr, j + 6, g, lane, a0, a1);
      tag_edge(rr, j + 7, g, lane, b0, b1);
    }
    for (; j + 2 <= cnt; j += 2) {
      tag_edge(rr, j + 0, g, lane, a0, a1);
      tag_edge(rr, j + 1, g, lane, b0, b1);
    }
    if (j < cnt) tag_edge(rr, j, g, lane, a0, a1);
  }
  float dn = dis[node];
  float r0v = dn * (a0 + b0), r1v = dn * (a1 + b1);
  u32 cin = *((const u32*)(Cin + (size_t)node * 128) + lane);
  r0v += bflo(cin); r1v += bfhi(cin);
  if (FINAL) {
    float2 bv = *(const float2*)(bias + 2 * lane);
    r0v = fmaxf(r0v + bv.x, 0.f);
    r1v = fmaxf(r1v + bv.y, 0.f);
  }
  *((u32*)(out + (size_t)node * 128) + lane) = packb2(r0v, r1v);
}

// ---------- EA gather v10: 1 node/wave, LDS-staged records, 8-edge unroll, fp8 P ----------
__global__ __launch_bounds__(256) void ea_gather10(
    const u16* __restrict__ pb, const u16* __restrict__ q,
    const u8* __restrict__ P /*fp8 [E,128]*/,
    const int* __restrict__ rowptr, const int4* __restrict__ cr,
    u16* __restrict__ Hsum, int N) {
  __shared__ int4 recs[4][64];
  int wave = threadIdx.x >> 6, lane = threadIdx.x & 63;
  int node = blockIdx.x * 4 + wave;
  if (node >= N) return;
  int e0 = rfl(rowptr[node]);
  int e1 = rfl(rowptr[node + 1]);
  int4* rr = recs[wave];
  u32 pbu = *((const u32*)(pb + (size_t)node * 128) + lane);
  float pb0 = bflo(pbu), pb1 = bfhi(pbu);
  float a0 = 0, a1 = 0, b0 = 0, b1 = 0;
  for (int base = e0; base < e1; base += 64) {
    if (base + lane < e1) rr[lane] = cr[base + lane];
    int cnt = min(64, e1 - base);
    int j = 0;
    for (; j + 8 <= cnt; j += 8) {
      ea_edge(rr, j + 0, q, P, lane, pb0, pb1, a0, a1);
      ea_edge(rr, j + 1, q, P, lane, pb0, pb1, b0, b1);
      ea_edge(rr, j + 2, q, P, lane, pb0, pb1, a0, a1);
      ea_edge(rr, j + 3, q, P, lane, pb0, pb1, b0, b1);
      ea_edge(rr, j + 4, q, P, lane, pb0, pb1, a0, a1);
      ea_edge(rr, j + 5, q, P, lane, pb0, pb1, b0, b1);
      ea_edge(rr, j + 6, q, P, lane, pb0, pb1, a0, a1);
      ea_edge(rr, j + 7, q, P, lane, pb0, pb1, b0, b1);
    }
    for (; j + 2 <= cnt; j += 2) {
      ea_edge(rr, j + 0, q, P, lane, pb0, pb1, a0, a1);
      ea_edge(rr, j + 1, q, P, lane, pb0, pb1, b0, b1);
    }
    if (j < cnt) ea_edge(rr, j, q, P, lane, pb0, pb1, a0, a1);
  }
  *((u32*)(Hsum + (size_t)node * 128) + lane) = packb2(a0 + b0, a1 + b1);
}

extern "C" void kernel_launch(void* const* d_in, const int* in_sizes, int n_in,
                              void* d_out, int out_size, void* d_ws, size_t ws_size,
                              hipStream_t stream) {
  const float* x      = (const float*)d_in[0];
  const float* mask   = (const float*)d_in[1];
  const float* ea     = (const float*)d_in[2];
  const int*   eidx   = (const int*)d_in[3];
  const float* m_w1   = (const float*)d_in[4];
  const float* m_b1   = (const float*)d_in[5];
  const float* m_w2   = (const float*)d_in[6];
  const float* m_b2   = (const float*)d_in[7];
  const float* ea0_w1 = (const float*)d_in[8];
  const float* ea0_b1 = (const float*)d_in[9];
  const float* ea0_w2 = (const float*)d_in[10];
  const float* ea0_b2 = (const float*)d_in[11];
  const float* tag0_w = (const float*)d_in[12];
  const float* tag0_b = (const float*)d_in[13];
  const float* ea1_w1 = (const float*)d_in[14];
  const float* ea1_b1 = (const float*)d_in[15];
  const float* ea1_w2 = (const float*)d_in[16];
  const float* ea1_b2 = (const float*)d_in[17];
  const float* tag1_w = (const float*)d_in[18];
  const float* tag1_b = (const float*)d_in[19];
  const float* ea2_w1 = (const float*)d_in[20];
  const float* ea2_b1 = (const float*)d_in[21];
  const float* ea2_w2 = (const float*)d_in[22];
  const float* ea2_b2 = (const float*)d_in[23];

  const int N = in_sizes[0] / 16;   // 20000
  const int E = in_sizes[2] / 16;   // 160000
  const int E2 = 2 * E;
  const int NB = (N + 255) / 256;

  char* w = (char*)d_ws;
  auto alloc = [&](size_t bytes) { char* p = w; w += (bytes + 255) & ~(size_t)255; return p; };
  int*   degi   = (int*)alloc((size_t)N * 4);
  int*   cursor = (int*)alloc((size_t)N * 4);
  int*   rowptr = (int*)alloc((size_t)(N + 1) * 4);
  int*   bsum   = (int*)alloc((size_t)256 * 4);
  float* dis    = (float*)alloc((size_t)N * 4);
  int4*  cr     = (int4*)alloc((size_t)E2 * 16);
  u16*   X0     = (u16*)alloc((size_t)N * 128 * 2);
  u16*   X1     = (u16*)alloc((size_t)N * 128 * 2);
  u16*   X2     = (u16*)alloc((size_t)N * 128 * 2);
  u16*   G0     = (u16*)alloc((size_t)N * 128 * 2);
  u16*   G1     = (u16*)alloc((size_t)N * 128 * 2);
  u16*   G2     = (u16*)alloc((size_t)N * 128 * 2);
  u16*   G3     = (u16*)alloc((size_t)N * 128 * 2);
  u16*   Wt     = (u16*)alloc((size_t)14 * 16384 * 2);
  u8*    P0     = (u8*)alloc((size_t)E * 128);
  u8*    P1     = (u8*)alloc((size_t)E * 128);
  u8*    P2     = (u8*)alloc((size_t)E * 128);
  (void)ws_size; (void)n_in; (void)out_size;

  const int EB = (E + 255) / 256;      // 625 proj chunks per table
  const int PB = 3 * EB;               // 1875 proj blocks
  const int CB = (E + 255) / 256;      // 625 count blocks
  const int FB = (E2 + 255) / 256;     // 1250 fill blocks
  const int HB = (N + 15) / 16;        // 1250 head blocks
  const int gm = (N + 63) / 64;
  const int g4 = (N + 3) / 4;
  const int gb = (N + 7) / 8;

  u16* WT_ea0w2  = Wt + 0 * 16384;
  u16* WT_tag0   = Wt + 1 * 16384;
  u16* WT_ea1d   = Wt + 5 * 16384;
  u16* WT_ea1s   = Wt + 6 * 16384;
  u16* WT_ea1w2  = Wt + 7 * 16384;
  u16* WT_tag1   = Wt + 8 * 16384;
  u16* WT_ea2d   = Wt + 12 * 16384;
  u16* WT_ea2s   = Wt + 13 * 16384;

  // ---- short critical path: count -> scan -> mega (proj+prep+fill+head overlapped) ----
  hipMemsetAsync(degi, 0, (size_t)N * 4, stream);
  count_deg<<<CB, 256, 0, stream>>>(eidx, degi, E);
  scan1<<<NB, 256, 0, stream>>>(degi, bsum, N);
  scan23<<<NB, 256, 0, stream>>>(degi, bsum, rowptr, cursor, dis, NB, N);
  mega<<<PB + 112 + FB + HB, 256, 0, stream>>>(
      ea, eidx, ea0_w1, ea0_b1, ea0_w2, tag0_w, ea1_w1, ea1_w2, tag1_w, ea2_w1,
      mask, x, m_w1, m_b1, m_w2, m_b2,
      P0, P1, P2, Wt, cursor, dis, cr, X0, X1, E, N, PB, FB, EB);

  // ---- EA0 + TAG0 GEMMs fused ----
  ea_gather10<<<g4, 256, 0, stream>>>(X0, X1, P0, rowptr, cr, X2, N);
  gemm_mfma_penta<<<gm, 256, 0, stream>>>(X2, WT_ea0w2, WT_tag0, ea0_b2, degi,
                                          G0, G1, G2, G3, N);
  tag_gather9<false><<<g4, 256, 0, stream>>>(G3, G2, nullptr, dis, rowptr, cr, X1, N);
  tag_gather9<false><<<g4, 256, 0, stream>>>(X1, G1, nullptr, dis, rowptr, cr, X2, N);
  tag_gather9<true><<<g4, 256, 0, stream>>>(X2, G0, tag0_b, dis, rowptr, cr, X0, N);  // h2 -> X0

  // ---- EA1 + TAG1 ----
  gemm_mfma_dual<<<gm, 256, 0, stream>>>(X0, WT_ea1d, WT_ea1s, X1, X2, ea1_b1, N);
  ea_gather10<<<g4, 256, 0, stream>>>(X1, X2, P1, rowptr, cr, G0, N);
  gemm_mfma_penta<<<gm, 256, 0, stream>>>(G0, WT_ea1w2, WT_tag1, ea1_b2, degi,
                                          G0, G1, G2, G3, N);   // in-place A=G0 safe
  tag_gather9<false><<<g4, 256, 0, stream>>>(G3, G2, nullptr, dis, rowptr, cr, X1, N);
  tag_gather9<false><<<g4, 256, 0, stream>>>(X1, G1, nullptr, dis, rowptr, cr, X2, N);
  tag_gather9<true><<<g4, 256, 0, stream>>>(X2, G0, tag1_b, dis, rowptr, cr, X0, N);  // h4 -> X0

  // ---- EA2 (final, out 16, fp32) ----
  gemm_mfma_dual<<<gm, 256, 0, stream>>>(X0, WT_ea2d, WT_ea2s, X1, X2, ea2_b1, N);
  ea_gather10<<<g4, 256, 0, stream>>>(X1, X2, P2, rowptr, cr, G0, N);
  gemm_tail<<<gb, 128, 0, stream>>>(G0, ea2_w2, (float*)d_out, ea2_b2, degi, N);
}

// Round 18
// 391.244 us; speedup vs baseline: 1.0346x; 1.0346x over previous
//
#include <hip/hip_runtime.h>

typedef unsigned short u16;
typedef unsigned char u8;
typedef unsigned int u32;

using bfrag  = __attribute__((ext_vector_type(8))) short;   // 8 bf16 (4 VGPRs)
using f32x2  = __attribute__((ext_vector_type(2))) float;
using f32x4  = __attribute__((ext_vector_type(4))) float;   // 4 fp32 acc
using f32x16 = __attribute__((ext_vector_type(16))) float;  // 16 fp32 acc (32x32 MFMA)

// ---------- bf16 / f16 / fp8 helpers ----------
__device__ __forceinline__ float b2f(u16 u) {
  union { u32 i; float f; } c; c.i = ((u32)u) << 16; return c.f;
}
__device__ __forceinline__ float bflo(u32 u) { union { u32 i; float f; } c; c.i = u << 16; return c.f; }
__device__ __forceinline__ float bfhi(u32 u) { union { u32 i; float f; } c; c.i = u & 0xffff0000u; return c.f; }
__device__ __forceinline__ u16 f2b(float f) {  // round-to-nearest-even
  union { float f; u32 i; } c; c.f = f;
  u32 x = c.i;
  u32 r = x + 0x7fffu + ((x >> 16) & 1u);
  return (u16)(r >> 16);
}
__device__ __forceinline__ u32 packb2(float x, float y) {
  return ((u32)f2b(x)) | (((u32)f2b(y)) << 16);
}
__device__ __forceinline__ int rfl(int v) { return __builtin_amdgcn_readfirstlane(v); }

// ---------- prologue: blocks [0,PB) proj (table x 256-edge chunk); [PB,PB+CB) count_deg; rest prep_wt ----------
__global__ __launch_bounds__(256) void prologue(
    const float* __restrict__ ea, const int* __restrict__ eidx,
    const float* __restrict__ ea0_w1, const float* __restrict__ ea0_w2,
    const float* __restrict__ tag0_w, const float* __restrict__ ea1_w1,
    const float* __restrict__ ea1_w2, const float* __restrict__ tag1_w,
    const float* __restrict__ ea2_w1,
    u8* __restrict__ P0, u8* __restrict__ P1, u8* __restrict__ P2,
    int* __restrict__ degi, u16* __restrict__ Wt, int E, int N,
    int PB, int CB, int EB) {
  int t = threadIdx.x;
  if (blockIdx.x < (unsigned)PB) {
    // ---- edge projection via MFMA 32x32x16: P[e,:] = ea[e,:16] @ W_tab (fp8 e4m3) ----
    __shared__ u16 Alds[256 * 16];   // 8 KB: 256 edges x 16 feats
    __shared__ u16 Wlds[2048];       // 4 KB: one table [128n][16k]
    int tab = blockIdx.x / EB;
    int chunk = blockIdx.x - tab * EB;
    int base = chunk * 256;
    int rows = E - base; if (rows > 256) rows = 256;
    const float* wsrc = (tab == 0) ? (ea0_w1 + 32 * 128)
                      : (tab == 1) ? (ea1_w1 + 256 * 128)
                                   : (ea2_w1 + 256 * 128);
    u8* P = (tab == 0) ? P0 : (tab == 1) ? P1 : P2;
#pragma unroll
    for (int i = 0; i < 8; ++i) {
      int idx = i * 256 + t;           // 0..2047
      int n = idx >> 4, k = idx & 15;
      Wlds[idx] = f2b(wsrc[k * 128 + n]);
    }
#pragma unroll
    for (int i = 0; i < 4; ++i) {
      int idx = (i * 256 + t) * 4;     // float index 0..4095
      float4 v = make_float4(0.f, 0.f, 0.f, 0.f);
      if ((idx >> 4) < rows) v = *(const float4*)(ea + (size_t)base * 16 + idx);
      ushort4 h;
      h.x = f2b(v.x); h.y = f2b(v.y); h.z = f2b(v.z); h.w = f2b(v.w);
      *(ushort4*)(Alds + idx) = h;
    }
    __syncthreads();
    int wave = t >> 6, lane = t & 63;
    int mm = lane & 31, kh = lane >> 5;
    // hoisted B fragments (adjacent-column pairs), reused across row-tiles
    bfrag b00 = *(const bfrag*)(Wlds + (2 * mm) * 16 + kh * 8);
    bfrag b01 = *(const bfrag*)(Wlds + (2 * mm + 1) * 16 + kh * 8);
    bfrag b10 = *(const bfrag*)(Wlds + (64 + 2 * mm) * 16 + kh * 8);
    bfrag b11 = *(const bfrag*)(Wlds + (64 + 2 * mm + 1) * 16 + kh * 8);
#pragma unroll
    for (int it = 0; it < 4; ++it) {
      int task = wave + it * 4;        // 0..15
      int rowt = (task >> 1) * 32;
      int ch = task & 1;
      int colt = ch * 64;
      bfrag a = *(const bfrag*)(Alds + (rowt + mm) * 16 + kh * 8);
      f32x16 acc0, acc1;
#pragma unroll
      for (int z = 0; z < 16; ++z) { acc0[z] = 0.f; acc1[z] = 0.f; }
      acc0 = __builtin_amdgcn_mfma_f32_32x32x16_bf16(a, ch ? b10 : b00, acc0, 0, 0, 0);
      acc1 = __builtin_amdgcn_mfma_f32_32x32x16_bf16(a, ch ? b11 : b01, acc1, 0, 0, 0);
#pragma unroll
      for (int reg = 0; reg < 16; ++reg) {
        int row = rowt + (reg & 3) + 8 * (reg >> 2) + 4 * kh;
        if (row < rows) {
          u32 pk = (u32)__builtin_amdgcn_cvt_pk_fp8_f32(acc0[reg], acc1[reg], 0, false);
          *(u16*)(P + (size_t)(base + row) * 128 + colt + 2 * mm) = (u16)pk;
        }
      }
    }
    return;
  }
  if (blockIdx.x < (unsigned)(PB + CB)) {
    // ---- count_deg (degi pre-zeroed by memset) ----
    int e = (blockIdx.x - PB) * 256 + t;
    if (e < E) {
      atomicAdd(&degi[eidx[E + e]], 1);
      atomicAdd(&degi[eidx[e]], 1);
    }
    return;
  }
  // ---- prep_wt: 14x fp32 [128][128] -> bf16 [n][k] ----
  int wb = blockIdx.x - PB - CB;          // 0..111
  int mat = wb >> 3, chunk = wb & 7;
  const float* src;
  if      (mat == 0)  src = ea0_w2;
  else if (mat <= 4)  src = tag0_w + (mat - 1) * 16384;
  else if (mat == 5)  src = ea1_w1;
  else if (mat == 6)  src = ea1_w1 + 16384;
  else if (mat == 7)  src = ea1_w2;
  else if (mat <= 11) src = tag1_w + (mat - 8) * 16384;
  else if (mat == 12) src = ea2_w1;
  else                src = ea2_w1 + 16384;
  u16* dst = Wt + mat * 16384;
  for (int i = 0; i < 8; ++i) {
    int idx = chunk * 2048 + i * 256 + t;
    int k = idx >> 7, n = idx & 127;
    dst[n * 128 + k] = f2b(src[idx]);
  }
}

// ---------- parallel scan ----------
__global__ __launch_bounds__(256) void scan1(const int* __restrict__ degi,
                                             int* __restrict__ bsum, int N) {
  __shared__ int sh[256];
  int t = threadIdx.x;
  int gid = blockIdx.x * 256 + t;
  sh[t] = (gid < N) ? degi[gid] : 0;
  __syncthreads();
  for (int off = 128; off > 0; off >>= 1) {
    if (t < off) sh[t] += sh[t + off];
    __syncthreads();
  }
  if (t == 0) bsum[blockIdx.x] = sh[0];
}

// scan2+scan3 merged
__global__ __launch_bounds__(256) void scan23(const int* __restrict__ degi,
                                              const int* __restrict__ bsum,
                                              int* __restrict__ rowptr,
                                              int* __restrict__ cursor,
                                              float* __restrict__ dis, int nb, int N) {
  __shared__ int sh[256];
  int t = threadIdx.x;
  int v = (t < nb) ? bsum[t] : 0;
  sh[t] = v;
  __syncthreads();
  for (int off = 1; off < 256; off <<= 1) {
    int x = sh[t];
    int add = (t >= off) ? sh[t - off] : 0;
    __syncthreads();
    sh[t] = x + add;
    __syncthreads();
  }
  int blockoff = (blockIdx.x == 0) ? 0 : sh[blockIdx.x - 1];
  int total = sh[nb - 1];
  __syncthreads();
  int gid = blockIdx.x * 256 + t;
  int d = (gid < N) ? degi[gid] : 0;
  sh[t] = d;
  __syncthreads();
  for (int off = 1; off < 256; off <<= 1) {
    int x = sh[t];
    int add = (t >= off) ? sh[t - off] : 0;
    __syncthreads();
    sh[t] = x + add;
    __syncthreads();
  }
  if (gid < N) {
    int run = blockoff + sh[t] - d;
    rowptr[gid] = run;
    cursor[gid] = run;
    dis[gid] = d > 0 ? rsqrtf((float)d) : 0.0f;
  }
  if (blockIdx.x == 0 && t == 0) rowptr[N] = total;
}

// ---------- fill_head: blocks [0,FB) fill_csr (2 edges/thread); [FB,FB+HB) head MLP ----------
__global__ __launch_bounds__(256) void fill_head(
    const int* __restrict__ eidx, int* __restrict__ cursor,
    const float* __restrict__ dis, int4* __restrict__ cr, int E,
    const float* __restrict__ mask, const float* __restrict__ x,
    const float* __restrict__ m_w1, const float* __restrict__ m_b1,
    const float* __restrict__ m_w2, const float* __restrict__ m_b2,
    const float* __restrict__ ea0_w1, const float* __restrict__ ea0_b1,
    u16* __restrict__ pb, u16* __restrict__ q, int M, int FB) {
  int t = threadIdx.x;
  if (blockIdx.x < (unsigned)FB) {
    // two independent edge chains per thread (MLP for the atomic latency)
    int E2 = 2 * E;
#pragma unroll
    for (int half = 0; half < 2; ++half) {
      int i = blockIdx.x * 512 + half * 256 + t;
      if (i < E2) {
        int e = (i < E) ? i : i - E;
        int s, d;
        if (i < E) { s = eidx[e]; d = eidx[E + e]; }
        else       { s = eidx[E + e]; d = eidx[e]; }
        int pos = atomicAdd(&cursor[d], 1);
        cr[pos] = make_int4(s, e, __float_as_int(dis[s]), 0);
      }
    }
    return;
  }
  // ---- head: h16 = relu(mask@w1+b1)@w2 + b2 + x; pb = h16@Wd + b1', q = h16@Ws ----
  __shared__ float Ml[16 * 16];
  __shared__ float T1[16 * 128];
  __shared__ float H[16 * 16];
  int base = (blockIdx.x - FB) * 16;
  {
    int r = t >> 4, k = t & 15;
    int row = base + r;
    Ml[t] = (row < M) ? mask[(size_t)row * 16 + k] : 0.f;
  }
  __syncthreads();
  {
    int col = t & 127, h2 = t >> 7;
    float acc[8];
    float b1v = m_b1[col];
#pragma unroll
    for (int r = 0; r < 8; ++r) acc[r] = b1v;
    for (int k = 0; k < 16; ++k) {
      float w = m_w1[k * 128 + col];
#pragma unroll
      for (int r = 0; r < 8; ++r) acc[r] += Ml[(h2 * 8 + r) * 16 + k] * w;
    }
#pragma unroll
    for (int r = 0; r < 8; ++r) T1[(h2 * 8 + r) * 128 + col] = fmaxf(acc[r], 0.f);
  }
  __syncthreads();
  {
    int r = t >> 4, u = t & 15;
    float acc = m_b2[u];
    for (int k = 0; k < 128; ++k) acc += T1[r * 128 + k] * m_w2[k * 16 + u];
    int row = base + r;
    float xv = (row < M) ? x[(size_t)row * 16 + u] : 0.f;
    H[t] = acc + xv;
  }
  __syncthreads();
  {
    int col = t & 127, h2 = t >> 7;
    float aP[8], aQ[8];
    float b1v = ea0_b1[col];
#pragma unroll
    for (int r = 0; r < 8; ++r) { aP[r] = b1v; aQ[r] = 0.f; }
    for (int k = 0; k < 16; ++k) {
      float wd = ea0_w1[k * 128 + col];
      float ws = ea0_w1[(16 + k) * 128 + col];
#pragma unroll
      for (int r = 0; r < 8; ++r) {
        float h = H[(h2 * 8 + r) * 16 + k];
        aP[r] += h * wd;
        aQ[r] += h * ws;
      }
    }
#pragma unroll
    for (int r = 0; r < 8; ++r) {
      int row = base + h2 * 8 + r;
      if (row < M) {
        pb[(size_t)row * 128 + col] = f2b(aP[r]);
        q[(size_t)row * 128 + col]  = f2b(aQ[r]);
      }
    }
  }
}

// ---------- dual MFMA GEMM: C0 = A@W0 (+bias0), C1 = A@W1 (both bf16) ----------
__global__ __launch_bounds__(256) void gemm_mfma_dual(
    const u16* __restrict__ A, const u16* __restrict__ W0t, const u16* __restrict__ W1t,
    u16* __restrict__ C0, u16* __restrict__ C1, const float* __restrict__ bias0, int M) {
  __shared__ u16 Alds[64 * 136];
  __shared__ u16 Wlds[128 * 136];
  int t = threadIdx.x;
  int base = blockIdx.x * 64;
#pragma unroll
  for (int i = 0; i < 8; ++i) {
    int idx = (i * 256 + t) * 8;
    int n = idx >> 7, k = idx & 127;
    uint4 v = *(const uint4*)(W0t + idx);
    *(uint4*)(Wlds + n * 136 + k) = v;
  }
#pragma unroll
  for (int i = 0; i < 4; ++i) {
    int idx = (i * 256 + t) * 8;
    int r = idx >> 7, k = idx & 127;
    int row = base + r;
    uint4 v = make_uint4(0, 0, 0, 0);
    if (row < M) v = *(const uint4*)(A + (size_t)row * 128 + k);
    *(uint4*)(Alds + r * 136 + k) = v;
  }
  __syncthreads();
  int wave = t >> 6, lane = t & 63;
  int m = lane & 15, quad = lane >> 4;
  int arow = wave * 16 + m;
  bfrag a[4];
#pragma unroll
  for (int ks = 0; ks < 4; ++ks)
    a[ks] = *(const bfrag*)(Alds + arow * 136 + ks * 32 + quad * 8);
  f32x4 acc0[8], acc1[8];
#pragma unroll
  for (int nt = 0; nt < 8; ++nt) { acc0[nt] = (f32x4){0,0,0,0}; acc1[nt] = (f32x4){0,0,0,0}; }
#pragma unroll
  for (int nt = 0; nt < 8; ++nt) {
    int n = nt * 16 + m;
#pragma unroll
    for (int ks = 0; ks < 4; ++ks) {
      bfrag b = *(const bfrag*)(Wlds + n * 136 + ks * 32 + quad * 8);
      acc0[nt] = __builtin_amdgcn_mfma_f32_16x16x32_bf16(a[ks], b, acc0[nt], 0, 0, 0);
    }
  }
  __syncthreads();
#pragma unroll
  for (int i = 0; i < 8; ++i) {
    int idx = (i * 256 + t) * 8;
    int n = idx >> 7, k = idx & 127;
    uint4 v = *(const uint4*)(W1t + idx);
    *(uint4*)(Wlds + n * 136 + k) = v;
  }
  __syncthreads();
#pragma unroll
  for (int nt = 0; nt < 8; ++nt) {
    int n = nt * 16 + m;
#pragma unroll
    for (int ks = 0; ks < 4; ++ks) {
      bfrag b = *(const bfrag*)(Wlds + n * 136 + ks * 32 + quad * 8);
      acc1[nt] = __builtin_amdgcn_mfma_f32_16x16x32_bf16(a[ks], b, acc1[nt], 0, 0, 0);
    }
  }
#pragma unroll
  for (int nt = 0; nt < 8; ++nt) {
    int col = nt * 16 + m;
#pragma unroll
    for (int r = 0; r < 4; ++r) {
      int row = base + wave * 16 + quad * 4 + r;
      if (row < M) {
        float v0 = acc0[nt][r];
        if (bias0) v0 += bias0[col];
        C0[(size_t)row * 128 + col] = f2b(v0);
        C1[(size_t)row * 128 + col] = f2b(acc1[nt][r]);
      }
    }
  }
}

// ---------- penta MFMA GEMM: h = relu(A@W2 + deg*bias); G_k = h @ W_k (k=0..3) ----------
__global__ __launch_bounds__(256) void gemm_mfma_penta(
    const u16* __restrict__ A, const u16* __restrict__ W2t, const u16* __restrict__ Wt4,
    const float* __restrict__ bias, const int* __restrict__ degi,
    u16* __restrict__ G0, u16* __restrict__ G1,
    u16* __restrict__ G2, u16* __restrict__ G3, int M) {
  __shared__ u16 Alds[64 * 136];
  __shared__ u16 Wlds[128 * 136];
  int t = threadIdx.x;
  int base = blockIdx.x * 64;
#pragma unroll
  for (int i = 0; i < 8; ++i) {
    int idx = (i * 256 + t) * 8;
    int n = idx >> 7, k = idx & 127;
    uint4 v = *(const uint4*)(W2t + idx);
    *(uint4*)(Wlds + n * 136 + k) = v;
  }
#pragma unroll
  for (int i = 0; i < 4; ++i) {
    int idx = (i * 256 + t) * 8;
    int r = idx >> 7, k = idx & 127;
    int row = base + r;
    uint4 v = make_uint4(0, 0, 0, 0);
    if (row < M) v = *(const uint4*)(A + (size_t)row * 128 + k);
    *(uint4*)(Alds + r * 136 + k) = v;
  }
  __syncthreads();
  int wave = t >> 6, lane = t & 63;
  int m = lane & 15, quad = lane >> 4;
  int arow = wave * 16 + m;
  bfrag a[4];
#pragma unroll
  for (int ks = 0; ks < 4; ++ks)
    a[ks] = *(const bfrag*)(Alds + arow * 136 + ks * 32 + quad * 8);
  {
    f32x4 acc[8];
#pragma unroll
    for (int nt = 0; nt < 8; ++nt) acc[nt] = (f32x4){0.f, 0.f, 0.f, 0.f};
#pragma unroll
    for (int nt = 0; nt < 8; ++nt) {
      int n = nt * 16 + m;
#pragma unroll
      for (int ks = 0; ks < 4; ++ks) {
        bfrag b = *(const bfrag*)(Wlds + n * 136 + ks * 32 + quad * 8);
        acc[nt] = __builtin_amdgcn_mfma_f32_16x16x32_bf16(a[ks], b, acc[nt], 0, 0, 0);
      }
    }
#pragma unroll
    for (int nt = 0; nt < 8; ++nt) {
      int col = nt * 16 + m;
#pragma unroll
      for (int r = 0; r < 4; ++r) {
        int lrow = wave * 16 + quad * 4 + r;
        int row = base + lrow;
        float v = 0.f;
        if (row < M) v = fmaxf(acc[nt][r] + bias[col] * (float)degi[row], 0.f);
        Alds[lrow * 136 + col] = f2b(v);   // own wave's slab; in-wave DS ordering
      }
    }
  }
#pragma unroll
  for (int ks = 0; ks < 4; ++ks)
    a[ks] = *(const bfrag*)(Alds + arow * 136 + ks * 32 + quad * 8);
#pragma unroll
  for (int mat = 0; mat < 4; ++mat) {
    __syncthreads();
#pragma unroll
    for (int i = 0; i < 8; ++i) {
      int idx = (i * 256 + t) * 8;
      int n = idx >> 7, k = idx & 127;
      uint4 v = *(const uint4*)(Wt4 + mat * 16384 + idx);
      *(uint4*)(Wlds + n * 136 + k) = v;
    }
    __syncthreads();
    f32x4 acc[8];
#pragma unroll
    for (int nt = 0; nt < 8; ++nt) acc[nt] = (f32x4){0.f, 0.f, 0.f, 0.f};
#pragma unroll
    for (int nt = 0; nt < 8; ++nt) {
      int n = nt * 16 + m;
#pragma unroll
      for (int ks = 0; ks < 4; ++ks) {
        bfrag b = *(const bfrag*)(Wlds + n * 136 + ks * 32 + quad * 8);
        acc[nt] = __builtin_amdgcn_mfma_f32_16x16x32_bf16(a[ks], b, acc[nt], 0, 0, 0);
      }
    }
    u16* G = (mat == 0) ? G0 : (mat == 1) ? G1 : (mat == 2) ? G2 : G3;
#pragma unroll
    for (int nt = 0; nt < 8; ++nt) {
      int col = nt * 16 + m;
#pragma unroll
      for (int r = 0; r < 4; ++r) {
        int row = base + wave * 16 + quad * 4 + r;
        if (row < M) G[(size_t)row * 128 + col] = f2b(acc[nt][r]);
      }
    }
  }
}

// ---------- VALU GEMM (final 128->16) ----------
__global__ __launch_bounds__(128) void gemm_tail(
    const u16* __restrict__ A, const float* __restrict__ W, float* __restrict__ Cout,
    const float* __restrict__ bias, const int* __restrict__ degi, int M) {
  const int ROWS = 8;
  int t = threadIdx.x;
  int base = blockIdx.x * ROWS;
  __shared__ float Al[ROWS * 128];
  for (int i = t; i < ROWS * 128; i += 128) {
    int r = i >> 7, k = i & 127;
    int row = base + r;
    Al[i] = (row < M) ? b2f(A[(size_t)row * 128 + k]) : 0.f;
  }
  __syncthreads();
  int r = t >> 4, u = t & 15;
  int row = base + r;
  float acc = 0.f;
  for (int k = 0; k < 128; ++k) acc += Al[r * 128 + k] * W[k * 16 + u];
  if (row < M) {
    Cout[(size_t)row * 16 + u] = acc + bias[u] * (float)degi[row];
  }
}

// ---------- per-edge bodies (unified int4 records in LDS) ----------
__device__ __forceinline__ void tag_edge(const int4* __restrict__ rr, int j,
    const u16* __restrict__ g, int lane, float& x0, float& x1) {
  int4 r = rr[j];
  int s = rfl(r.x); float w = __uint_as_float(rfl(r.z));
  u32 h = *((const u32*)(g + (size_t)s * 128) + lane);
  x0 += w * bflo(h); x1 += w * bfhi(h);
}
__device__ __forceinline__ void ea_edge(const int4* __restrict__ rr, int j,
    const u16* __restrict__ q, const u8* __restrict__ P8, int lane,
    float pb0, float pb1, float& x0, float& x1) {
  int4 r = rr[j];
  int s = rfl(r.x), i = rfl(r.y);
  u32 qv = *((const u32*)(q + (size_t)s * 128) + lane);
  u16 pv = *((const u16*)(P8 + (size_t)i * 128) + lane);
  f32x2 pf = __builtin_amdgcn_cvt_pk_f32_fp8((int)pv, false);
  x0 += fmaxf(pb0 + bflo(qv) + pf.x, 0.f);
  x1 += fmaxf(pb1 + bfhi(qv) + pf.y, 0.f);
}

// ---------- TAG gather v9: 1 node/wave, LDS-staged 64-record batches, 8-edge unroll ----------
template<bool FINAL>
__global__ __launch_bounds__(256) void tag_gather9(
    const u16* __restrict__ g, const u16* __restrict__ Cin,
    const float* __restrict__ bias, const float* __restrict__ dis,
    const int* __restrict__ rowptr, const int4* __restrict__ cr,
    u16* __restrict__ out, int N) {
  __shared__ int4 recs[4][64];
  int wave = threadIdx.x >> 6, lane = threadIdx.x & 63;
  int node = blockIdx.x * 4 + wave;
  if (node >= N) return;
  int e0 = rfl(rowptr[node]);
  int e1 = rfl(rowptr[node + 1]);
  int4* rr = recs[wave];
  float a0 = 0, a1 = 0, b0 = 0, b1 = 0;
  for (int base = e0; base < e1; base += 64) {
    if (base + lane < e1) rr[lane] = cr[base + lane];
    int cnt = min(64, e1 - base);
    int j = 0;
    for (; j + 8 <= cnt; j += 8) {
      tag_edge(rr, j + 0, g, lane, a0, a1);
      tag_edge(rr, j + 1, g, lane, b0, b1);
      tag_edge(rr, j + 2, g, lane, a0, a1);
      tag_edge(rr, j + 3, g, lane, b0, b1);
      tag_edge(rr, j + 4, g, lane, a0, a1);
      tag_edge(rr, j + 5, g, lane, b0, b1);
      tag_edge(rr, j + 6, g, lane, a0, a1);
      tag_edge(rr, j + 7, g, lane, b0, b1);
    }
    for (; j + 2 <= cnt; j += 2) {
      tag_edge(rr, j + 0, g, lane, a0, a1);
      tag_edge(rr, j + 1, g, lane, b0, b1);
    }
    if (j < cnt) tag_edge(rr, j, g, lane, a0, a1);
  }
  float dn = dis[node];
  float r0v = dn * (a0 + b0), r1v = dn * (a1 + b1);
  u32 cin = *((const u32*)(Cin + (size_t)node * 128) + lane);
  r0v += bflo(cin); r1v += bfhi(cin);
  if (FINAL) {
    float2 bv = *(const float2*)(bias + 2 * lane);
    r0v = fmaxf(r0v + bv.x, 0.f);
    r1v = fmaxf(r1v + bv.y, 0.f);
  }
  *((u32*)(out + (size_t)node * 128) + lane) = packb2(r0v, r1v);
}

// ---------- EA gather v10: 1 node/wave, LDS-staged records, 8-edge unroll, fp8 P ----------
__global__ __launch_bounds__(256) void ea_gather10(
    const u16* __restrict__ pb, const u16* __restrict__ q,
    const u8* __restrict__ P /*fp8 [E,128]*/,
    const int* __restrict__ rowptr, const int4* __restrict__ cr,
    u16* __restrict__ Hsum, int N) {
  __shared__ int4 recs[4][64];
  int wave = threadIdx.x >> 6, lane = threadIdx.x & 63;
  int node = blockIdx.x * 4 + wave;
  if (node >= N) return;
  int e0 = rfl(rowptr[node]);
  int e1 = rfl(rowptr[node + 1]);
  int4* rr = recs[wave];
  u32 pbu = *((const u32*)(pb + (size_t)node * 128) + lane);
  float pb0 = bflo(pbu), pb1 = bfhi(pbu);
  float a0 = 0, a1 = 0, b0 = 0, b1 = 0;
  for (int base = e0; base < e1; base += 64) {
    if (base + lane < e1) rr[lane] = cr[base + lane];
    int cnt = min(64, e1 - base);
    int j = 0;
    for (; j + 8 <= cnt; j += 8) {
      ea_edge(rr, j + 0, q, P, lane, pb0, pb1, a0, a1);
      ea_edge(rr, j + 1, q, P, lane, pb0, pb1, b0, b1);
      ea_edge(rr, j + 2, q, P, lane, pb0, pb1, a0, a1);
      ea_edge(rr, j + 3, q, P, lane, pb0, pb1, b0, b1);
      ea_edge(rr, j + 4, q, P, lane, pb0, pb1, a0, a1);
      ea_edge(rr, j + 5, q, P, lane, pb0, pb1, b0, b1);
      ea_edge(rr, j + 6, q, P, lane, pb0, pb1, a0, a1);
      ea_edge(rr, j + 7, q, P, lane, pb0, pb1, b0, b1);
    }
    for (; j + 2 <= cnt; j += 2) {
      ea_edge(rr, j + 0, q, P, lane, pb0, pb1, a0, a1);
      ea_edge(rr, j + 1, q, P, lane, pb0, pb1, b0, b1);
    }
    if (j < cnt) ea_edge(rr, j, q, P, lane, pb0, pb1, a0, a1);
  }
  *((u32*)(Hsum + (size_t)node * 128) + lane) = packb2(a0 + b0, a1 + b1);
}

extern "C" void kernel_launch(void* const* d_in, const int* in_sizes, int n_in,
                              void* d_out, int out_size, void* d_ws, size_t ws_size,
                              hipStream_t stream) {
  const float* x      = (const float*)d_in[0];
  const float* mask   = (const float*)d_in[1];
  const float* ea     = (const float*)d_in[2];
  const int*   eidx   = (const int*)d_in[3];
  const float* m_w1   = (const float*)d_in[4];
  const float* m_b1   = (const float*)d_in[5];
  const float* m_w2   = (const float*)d_in[6];
  const float* m_b2   = (const float*)d_in[7];
  const float* ea0_w1 = (const float*)d_in[8];
  const float* ea0_b1 = (const float*)d_in[9];
  const float* ea0_w2 = (const float*)d_in[10];
  const float* ea0_b2 = (const float*)d_in[11];
  const float* tag0_w = (const float*)d_in[12];
  const float* tag0_b = (const float*)d_in[13];
  const float* ea1_w1 = (const float*)d_in[14];
  const float* ea1_b1 = (const float*)d_in[15];
  const float* ea1_w2 = (const float*)d_in[16];
  const float* ea1_b2 = (const float*)d_in[17];
  const float* tag1_w = (const float*)d_in[18];
  const float* tag1_b = (const float*)d_in[19];
  const float* ea2_w1 = (const float*)d_in[20];
  const float* ea2_b1 = (const float*)d_in[21];
  const float* ea2_w2 = (const float*)d_in[22];
  const float* ea2_b2 = (const float*)d_in[23];

  const int N = in_sizes[0] / 16;   // 20000
  const int E = in_sizes[2] / 16;   // 160000
  const int E2 = 2 * E;
  const int NB = (N + 255) / 256;

  char* w = (char*)d_ws;
  auto alloc = [&](size_t bytes) { char* p = w; w += (bytes + 255) & ~(size_t)255; return p; };
  int*   degi   = (int*)alloc((size_t)N * 4);
  int*   cursor = (int*)alloc((size_t)N * 4);
  int*   rowptr = (int*)alloc((size_t)(N + 1) * 4);
  int*   bsum   = (int*)alloc((size_t)256 * 4);
  float* dis    = (float*)alloc((size_t)N * 4);
  int4*  cr     = (int4*)alloc((size_t)E2 * 16);
  u16*   X0     = (u16*)alloc((size_t)N * 128 * 2);
  u16*   X1     = (u16*)alloc((size_t)N * 128 * 2);
  u16*   X2     = (u16*)alloc((size_t)N * 128 * 2);
  u16*   G0     = (u16*)alloc((size_t)N * 128 * 2);
  u16*   G1     = (u16*)alloc((size_t)N * 128 * 2);
  u16*   G2     = (u16*)alloc((size_t)N * 128 * 2);
  u16*   G3     = (u16*)alloc((size_t)N * 128 * 2);
  u16*   Wt     = (u16*)alloc((size_t)14 * 16384 * 2);
  u8*    P0     = (u8*)alloc((size_t)E * 128);
  u8*    P1     = (u8*)alloc((size_t)E * 128);
  u8*    P2     = (u8*)alloc((size_t)E * 128);
  (void)ws_size; (void)n_in; (void)out_size;

  const int EB = (E + 255) / 256;      // 625 proj chunks per table
  const int PB = 3 * EB;               // 1875 proj blocks
  const int CB = (E + 255) / 256;      // 625 count blocks
  const int FB = (E2 + 511) / 512;     // 625 fill blocks (2 edges/thread)
  const int HB = (N + 15) / 16;        // 1250 head blocks
  const int gm = (N + 63) / 64;
  const int g4 = (N + 3) / 4;
  const int gb = (N + 7) / 8;

  u16* WT_ea0w2  = Wt + 0 * 16384;
  u16* WT_tag0   = Wt + 1 * 16384;
  u16* WT_ea1d   = Wt + 5 * 16384;
  u16* WT_ea1s   = Wt + 6 * 16384;
  u16* WT_ea1w2  = Wt + 7 * 16384;
  u16* WT_tag1   = Wt + 8 * 16384;
  u16* WT_ea2d   = Wt + 12 * 16384;
  u16* WT_ea2s   = Wt + 13 * 16384;

  // ---- prologue: proj + count + weight prep (degi zeroed by memset) ----
  hipMemsetAsync(degi, 0, (size_t)N * 4, stream);
  prologue<<<PB + CB + 112, 256, 0, stream>>>(ea, eidx, ea0_w1, ea0_w2, tag0_w,
                                              ea1_w1, ea1_w2, tag1_w, ea2_w1,
                                              P0, P1, P2, degi, Wt, E, N, PB, CB, EB);
  scan1<<<NB, 256, 0, stream>>>(degi, bsum, N);
  scan23<<<NB, 256, 0, stream>>>(degi, bsum, rowptr, cursor, dis, NB, N);
  fill_head<<<FB + HB, 256, 0, stream>>>(eidx, cursor, dis, cr, E,
                                         mask, x, m_w1, m_b1, m_w2, m_b2,
                                         ea0_w1, ea0_b1, X0, X1, N, FB);

  // ---- EA0 + TAG0 GEMMs fused ----
  ea_gather10<<<g4, 256, 0, stream>>>(X0, X1, P0, rowptr, cr, X2, N);
  gemm_mfma_penta<<<gm, 256, 0, stream>>>(X2, WT_ea0w2, WT_tag0, ea0_b2, degi,
                                          G0, G1, G2, G3, N);
  tag_gather9<false><<<g4, 256, 0, stream>>>(G3, G2, nullptr, dis, rowptr, cr, X1, N);
  tag_gather9<false><<<g4, 256, 0, stream>>>(X1, G1, nullptr, dis, rowptr, cr, X2, N);
  tag_gather9<true><<<g4, 256, 0, stream>>>(X2, G0, tag0_b, dis, rowptr, cr, X0, N);  // h2 -> X0

  // ---- EA1 + TAG1 ----
  gemm_mfma_dual<<<gm, 256, 0, stream>>>(X0, WT_ea1d, WT_ea1s, X1, X2, ea1_b1, N);
  ea_gather10<<<g4, 256, 0, stream>>>(X1, X2, P1, rowptr, cr, G0, N);
  gemm_mfma_penta<<<gm, 256, 0, stream>>>(G0, WT_ea1w2, WT_tag1, ea1_b2, degi,
                                          G0, G1, G2, G3, N);   // in-place A=G0 safe
  tag_gather9<false><<<g4, 256, 0, stream>>>(G3, G2, nullptr, dis, rowptr, cr, X1, N);
  tag_gather9<false><<<g4, 256, 0, stream>>>(X1, G1, nullptr, dis, rowptr, cr, X2, N);
  tag_gather9<true><<<g4, 256, 0, stream>>>(X2, G0, tag1_b, dis, rowptr, cr, X0, N);  // h4 -> X0

  // ---- EA2 (final, out 16, fp32) ----
  gemm_mfma_dual<<<gm, 256, 0, stream>>>(X0, WT_ea2d, WT_ea2s, X1, X2, ea2_b1, N);
  ea_gather10<<<g4, 256, 0, stream>>>(X1, X2, P2, rowptr, cr, G0, N);
  gemm_tail<<<gb, 128, 0, stream>>>(G0, ea2_w2, (float*)d_out, ea2_b2, degi, N);
}